// Round 1
// baseline (641.897 us; speedup 1.0000x reference)
//
#include <hip/hip_runtime.h>
#include <hip/hip_bf16.h>
#include <stdint.h>

typedef __attribute__((ext_vector_type(8))) short bf16x8;
typedef __attribute__((ext_vector_type(4))) float f32x4;

#define N_IMG 32
#define C_IN  512
#define HW    3136
#define WIMG  56
#define C_SQ  64
#define C_E   256

// RNE fp32 -> bf16 (finite inputs only)
static __device__ __forceinline__ unsigned short f2bf(float f) {
    unsigned u = __builtin_bit_cast(unsigned, f);
    unsigned r = (u + 0x7FFFu + ((u >> 16) & 1u)) >> 16;
    return (unsigned short)r;
}

// ---------------- prep: cast/repack weights to bf16 ----------------
// wsq_bf[64][512]; w1_bf[256][64]; w3r_bf[j=9][256][64] from w3[o][c][ky][kx]
__global__ void prep_weights(const float* __restrict__ wsq,
                             const float* __restrict__ w1,
                             const float* __restrict__ w3,
                             unsigned short* __restrict__ wsq_bf,
                             unsigned short* __restrict__ w1_bf,
                             unsigned short* __restrict__ w3r_bf) {
    int t = blockIdx.x * 256 + threadIdx.x;
    if (t < 32768) wsq_bf[t] = f2bf(wsq[t]);
    if (t < 16384) w1_bf[t] = f2bf(w1[t]);
    if (t < 147456) {
        int j = t >> 14;            // 0..8
        int rem = t & 16383;
        int o = rem >> 6, c = rem & 63;
        w3r_bf[t] = f2bf(w3[(o * 64 + c) * 9 + j]);
    }
}

// ---------------- squeeze: s[n][hw][c] (NHWC bf16) = relu(Wsq @ X + b) ----------------
// grid (49, 32), block 256 (4 waves). Block computes all 64 channels x 64 cols.
__global__ __launch_bounds__(256, 2) void squeeze_kernel(
    const float* __restrict__ x, const float* __restrict__ b_sq,
    const unsigned short* __restrict__ wsq_bf, unsigned short* __restrict__ s)
{
    const int n   = blockIdx.y;
    const int hw0 = blockIdx.x * 64;
    const int w   = threadIdx.x >> 6;
    const int l   = threadIdx.x & 63;
    const int lx  = l & 15, lk = l >> 4;

    const float* Xn = x + (size_t)n * C_IN * HW;
    f32x4 acc[4] = {};
    const unsigned short* ap = wsq_bf + (16 * w + lx) * C_IN + lk * 8;

    for (int k0 = 0; k0 < C_IN; k0 += 32) {
        bf16x8 a = *(const bf16x8*)(ap + k0);
        const float* rp = Xn + (size_t)(k0 + lk * 8) * HW + hw0 + lx;
        float fv[4][8];
        #pragma unroll
        for (int i = 0; i < 8; ++i) {
            #pragma unroll
            for (int nf = 0; nf < 4; ++nf) fv[nf][i] = rp[nf * 16];
            rp += HW;
        }
        #pragma unroll
        for (int nf = 0; nf < 4; ++nf) {
            bf16x8 b;
            #pragma unroll
            for (int i = 0; i < 8; ++i) b[i] = (short)f2bf(fv[nf][i]);
            acc[nf] = __builtin_amdgcn_mfma_f32_16x16x32_bf16(a, b, acc[nf], 0, 0, 0);
        }
    }

    const int c0 = 16 * w + lk * 4;
    float4 bias = *(const float4*)(b_sq + c0);
    const float* bp = (const float*)&bias;
    #pragma unroll
    for (int nf = 0; nf < 4; ++nf) {
        int col = hw0 + nf * 16 + lx;
        unsigned short v[4];
        #pragma unroll
        for (int r = 0; r < 4; ++r) {
            float val = fmaxf(acc[nf][r] + bp[r], 0.0f);
            v[r] = f2bf(val);
        }
        uint2 pk;
        pk.x = (unsigned)v[0] | ((unsigned)v[1] << 16);
        pk.y = (unsigned)v[2] | ((unsigned)v[3] << 16);
        *(uint2*)(s + ((size_t)n * HW + col) * C_SQ + c0) = pk;
    }
}

// ---------------- expand: both branches, 64 c_out x 64 cols per block ----------------
// grid (49, 4, 32), block 256 (4 waves).
__global__ __launch_bounds__(256, 2) void expand_kernel(
    const unsigned short* __restrict__ s,
    const unsigned short* __restrict__ w1_bf,
    const unsigned short* __restrict__ w3r_bf,
    const float* __restrict__ b1, const float* __restrict__ b3,
    float* __restrict__ out)
{
    const int n   = blockIdx.z;
    const int mt  = blockIdx.y;      // 0..3
    const int hw0 = blockIdx.x * 64;
    const int w   = threadIdx.x >> 6;
    const int l   = threadIdx.x & 63;
    const int lx  = l & 15, lk = l >> 4;

    const int row = 64 * mt + 16 * w + lx;   // A row (c_out within branch)
    const unsigned short* sn = s + (size_t)n * HW * C_SQ;

    int col[4], yy[4], xx[4];
    const unsigned short* sp[4];
    #pragma unroll
    for (int nf = 0; nf < 4; ++nf) {
        col[nf] = hw0 + nf * 16 + lx;
        yy[nf] = col[nf] / WIMG;
        xx[nf] = col[nf] % WIMG;
        sp[nf] = sn + (size_t)col[nf] * C_SQ + lk * 8;
    }

    float* outn = out + (size_t)n * 512 * HW;
    const int c0 = 64 * mt + 16 * w + lk * 4;

    // ---- e1 (K = 64) ----
    {
        f32x4 acc[4] = {};
        #pragma unroll
        for (int k0 = 0; k0 < 64; k0 += 32) {
            bf16x8 a = *(const bf16x8*)(w1_bf + row * 64 + k0 + lk * 8);
            #pragma unroll
            for (int nf = 0; nf < 4; ++nf) {
                bf16x8 b = *(const bf16x8*)(sp[nf] + k0);
                acc[nf] = __builtin_amdgcn_mfma_f32_16x16x32_bf16(a, b, acc[nf], 0, 0, 0);
            }
        }
        float4 bias = *(const float4*)(b1 + c0);
        const float* bp = (const float*)&bias;
        #pragma unroll
        for (int nf = 0; nf < 4; ++nf) {
            #pragma unroll
            for (int r = 0; r < 4; ++r) {
                float v = fmaxf(acc[nf][r] + bp[r], 0.0f);
                outn[(size_t)(c0 + r) * HW + col[nf]] = v;
            }
        }
    }

    // ---- e3 (implicit GEMM, K = 9*64, zero padding) ----
    {
        f32x4 acc[4] = {};
        #pragma unroll
        for (int j = 0; j < 9; ++j) {
            const int dy = j / 3 - 1, dx = j % 3 - 1;
            const int doff = (dy * WIMG + dx) * C_SQ;
            bool valid[4];
            #pragma unroll
            for (int nf = 0; nf < 4; ++nf)
                valid[nf] = ((unsigned)(yy[nf] + dy) < (unsigned)WIMG) &&
                            ((unsigned)(xx[nf] + dx) < (unsigned)WIMG);
            const unsigned short* wj = w3r_bf + j * 16384 + row * 64;
            #pragma unroll
            for (int k0 = 0; k0 < 64; k0 += 32) {
                bf16x8 a = *(const bf16x8*)(wj + k0 + lk * 8);
                #pragma unroll
                for (int nf = 0; nf < 4; ++nf) {
                    bf16x8 b = {0, 0, 0, 0, 0, 0, 0, 0};
                    if (valid[nf]) b = *(const bf16x8*)(sp[nf] + doff + k0);
                    acc[nf] = __builtin_amdgcn_mfma_f32_16x16x32_bf16(a, b, acc[nf], 0, 0, 0);
                }
            }
        }
        float4 bias = *(const float4*)(b3 + c0);
        const float* bp = (const float*)&bias;
        #pragma unroll
        for (int nf = 0; nf < 4; ++nf) {
            #pragma unroll
            for (int r = 0; r < 4; ++r) {
                float v = fmaxf(acc[nf][r] + bp[r], 0.0f);
                outn[(size_t)(256 + c0 + r) * HW + col[nf]] = v;
            }
        }
    }
}

extern "C" void kernel_launch(void* const* d_in, const int* in_sizes, int n_in,
                              void* d_out, int out_size, void* d_ws, size_t ws_size,
                              hipStream_t stream) {
    const float* x   = (const float*)d_in[0];
    const float* wsq = (const float*)d_in[1];
    const float* bsq = (const float*)d_in[2];
    const float* w1  = (const float*)d_in[3];
    const float* b1  = (const float*)d_in[4];
    const float* w3  = (const float*)d_in[5];
    const float* b3  = (const float*)d_in[6];
    float* out = (float*)d_out;

    unsigned short* wsq_bf = (unsigned short*)d_ws;       // 32768
    unsigned short* w1_bf  = wsq_bf + 32768;              // 16384
    unsigned short* w3r_bf = w1_bf + 16384;               // 147456
    unsigned short* s      = w3r_bf + 147456;             // 32*3136*64 bf16 (NHWC)

    prep_weights<<<576, 256, 0, stream>>>(wsq, w1, w3, wsq_bf, w1_bf, w3r_bf);
    squeeze_kernel<<<dim3(49, 32), 256, 0, stream>>>(x, bsq, wsq_bf, s);
    expand_kernel<<<dim3(49, 4, 32), 256, 0, stream>>>(s, w1_bf, w3r_bf, b1, b3, out);
}

// Round 2
// 429.339 us; speedup vs baseline: 1.4951x; 1.4951x over previous
//
#include <hip/hip_runtime.h>
#include <hip/hip_bf16.h>
#include <stdint.h>

typedef __attribute__((ext_vector_type(8))) short bf16x8;
typedef __attribute__((ext_vector_type(4))) float f32x4;

#define GLB(p) ((const __attribute__((address_space(1))) void*)(p))
#define LDSP(p) ((__attribute__((address_space(3))) void*)(p))

#define HW    3136
#define WIMG  56
#define PROW  58                 // padded row length (56 + 2 halo)
#define PNR   59                 // padded rows allocated (58 used + 1 overread row)
#define SIMG  (PNR * PROW)       // 3422 cells/image, 128 B each
#define C_IN  512

// RNE fp32 -> bf16
static __device__ __forceinline__ unsigned short f2bf(float f) {
    unsigned u = __builtin_bit_cast(unsigned, f);
    return (unsigned short)((u + 0x7FFFu + ((u >> 16) & 1u)) >> 16);
}

// ---------------- zero s (halo must be 0; ws is poisoned 0xAA every call) ----------------
__global__ void zero_s(uint4* __restrict__ s) {
    const unsigned total = 32u * SIMG * 8;   // 16B chunks
    for (unsigned i = blockIdx.x * 256 + threadIdx.x; i < total; i += gridDim.x * 256) {
        uint4 z; z.x = z.y = z.z = z.w = 0;
        s[i] = z;
    }
}

// ---------------- prep: cast/repack weights to bf16 ----------------
// wsq_bf[64][512]; w1_bf[256][64]; w3r_bf[j=9][256][64] from w3[o][c][ky][kx]
__global__ void prep_weights(const float* __restrict__ wsq,
                             const float* __restrict__ w1,
                             const float* __restrict__ w3,
                             unsigned short* __restrict__ wsq_bf,
                             unsigned short* __restrict__ w1_bf,
                             unsigned short* __restrict__ w3r_bf) {
    int t = blockIdx.x * 256 + threadIdx.x;
    if (t < 32768) wsq_bf[t] = f2bf(wsq[t]);
    if (t < 16384) w1_bf[t] = f2bf(w1[t]);
    if (t < 147456) {
        int j = t >> 14;
        int rem = t & 16383;
        int o = rem >> 6, c = rem & 63;
        w3r_bf[t] = f2bf(w3[(o * 64 + c) * 9 + j]);
    }
}

// ---------------- squeeze: s[n][p][c] (padded, swizzled NHWC bf16) ----------------
// grid (49, 32), block 256 (4 waves). Block: 64 out-ch x 64 cols, K=512.
// LDS: double-buffered 32ch x 64col fp32 tiles staged via global_load_lds with
// pre-swizzled SOURCE (byte ^= ((row>>3)&3)<<6) so strided f32 reads are ~conflict-free.
__global__ __launch_bounds__(256, 4) void squeeze_kernel(
    const float* __restrict__ x, const float* __restrict__ b_sq,
    const unsigned short* __restrict__ wsq_bf, unsigned short* __restrict__ s)
{
    __shared__ uint8_t xs[2][8192];
    const int n = blockIdx.y, hw0 = blockIdx.x * 64;
    const int tid = threadIdx.x;
    const int w = tid >> 6, l = tid & 63, lx = l & 15, lk = l >> 4;

    const uint8_t* xbase = (const uint8_t*)(x + (size_t)n * C_IN * HW + hw0);

    auto stage = [&](int buf, int kb) {
        #pragma unroll
        for (int q = 0; q < 2; ++q) {
            int c = q * 256 + tid;            // 16B chunk 0..511
            int r = c >> 4, g = c & 15;       // r: channel row 0..31
            const uint8_t* src = xbase + (size_t)(kb * 32 + r) * (HW * 4)
                                       + ((g * 16) ^ (((r >> 3) & 3) << 6));
            __builtin_amdgcn_global_load_lds(GLB(src), LDSP(&xs[buf][c * 16]), 16, 0, 0);
        }
    };

    stage(0, 0);
    __syncthreads();

    f32x4 acc[4] = {};
    const unsigned short* ap = wsq_bf + (16 * w + lx) * C_IN + lk * 8;
    const int swz = lk << 6;

    for (int kb = 0; kb < 16; ++kb) {
        const int cur = kb & 1;
        if (kb < 15) stage(cur ^ 1, kb + 1);
        bf16x8 a = *(const bf16x8*)(ap + kb * 32);
        #pragma unroll
        for (int nf = 0; nf < 4; ++nf) {
            const uint8_t* base = &xs[cur][lk * 2048 + (((nf * 16 + lx) * 4) ^ swz)];
            float f[8];
            #pragma unroll
            for (int i = 0; i < 8; ++i) f[i] = *(const float*)(base + i * 256);
            union { uint32_t u[4]; bf16x8 v; } bb;
            #pragma unroll
            for (int h = 0; h < 4; ++h)
                asm("v_cvt_pk_bf16_f32 %0, %1, %2" : "=v"(bb.u[h]) : "v"(f[2*h]), "v"(f[2*h+1]));
            acc[nf] = __builtin_amdgcn_mfma_f32_16x16x32_bf16(a, bb.v, acc[nf], 0, 0, 0);
        }
        __syncthreads();
    }

    const int c0 = 16 * w + lk * 4;
    float4 bias = *(const float4*)(b_sq + c0);
    const float* bp = (const float*)&bias;
    uint8_t* sn = (uint8_t*)s + (size_t)n * SIMG * 128;
    #pragma unroll
    for (int nf = 0; nf < 4; ++nf) {
        int col = hw0 + nf * 16 + lx;
        int p = col + 59 + 2 * (col / WIMG);      // padded linear index
        unsigned short v[4];
        #pragma unroll
        for (int r = 0; r < 4; ++r) v[r] = f2bf(fmaxf(acc[nf][r] + bp[r], 0.0f));
        uint2 pk;
        pk.x = (unsigned)v[0] | ((unsigned)v[1] << 16);
        pk.y = (unsigned)v[2] | ((unsigned)v[3] << 16);
        *(uint2*)(sn + (size_t)p * 128 + ((c0 * 2) ^ ((p & 7) << 4))) = pk;
    }
}

// ---------------- expand: operand-swapped MFMA, LDS-staged s tile ----------------
// grid (49, 4, 32), block 256 (4 waves). Block: 64 c_out (mt) x 64 cols, both branches.
// Wave: 16 c_out x 64 cols. Tile: 5 padded rows x 58 cols x 128 B = 37120 B (contiguous
// in global; swizzle inherited from squeeze's pre-swizzled writes).
__global__ __launch_bounds__(256, 4) void expand_kernel(
    const unsigned short* __restrict__ s,
    const unsigned short* __restrict__ w1_bf,
    const unsigned short* __restrict__ w3r_bf,
    const float* __restrict__ b1, const float* __restrict__ b3,
    float* __restrict__ out)
{
    __shared__ uint8_t tile[37120];
    const int n = blockIdx.z, mt = blockIdx.y, hw0 = blockIdx.x * 64;
    const int tid = threadIdx.x;
    const int w = tid >> 6, l = tid & 63, lx = l & 15, lk = l >> 4;
    const int y0 = hw0 / WIMG;

    const uint8_t* src = (const uint8_t*)s + ((size_t)n * SIMG + y0 * PROW) * 128;
    #pragma unroll
    for (int it = 0; it < 9; ++it) {
        int c = it * 256 + tid;
        __builtin_amdgcn_global_load_lds(GLB(src + (size_t)c * 16), LDSP(&tile[c * 16]), 16, 0, 0);
    }
    if (tid < 16)
        __builtin_amdgcn_global_load_lds(GLB(src + (size_t)(2304 + tid) * 16),
                                         LDSP(&tile[(2304 + tid) * 16]), 16, 0, 0);
    __syncthreads();

    int pg[4], tb[4];
    #pragma unroll
    for (int nf = 0; nf < 4; ++nf) {
        int hw = hw0 + nf * 16 + lx;
        int p = hw + 59 + 2 * (hw / WIMG);
        pg[nf] = p;
        tb[nf] = (p - y0 * PROW) * 128;
    }
    const int cb = 64 * mt + 16 * w;
    const int lk16 = lk * 16;
    float* outn = out + (size_t)n * 512 * HW;

    // ---- e1 (K=64) ----
    {
        f32x4 acc[4] = {};
        #pragma unroll
        for (int k0 = 0; k0 < 2; ++k0) {
            bf16x8 b = *(const bf16x8*)(w1_bf + (cb + lx) * 64 + k0 * 32 + lk * 8);
            #pragma unroll
            for (int nf = 0; nf < 4; ++nf) {
                int sw = (pg[nf] & 7) << 4;
                bf16x8 a = *(const bf16x8*)&tile[tb[nf] + ((lk16 + k0 * 64) ^ sw)];
                acc[nf] = __builtin_amdgcn_mfma_f32_16x16x32_bf16(a, b, acc[nf], 0, 0, 0);
            }
        }
        float bias = b1[cb + lx];
        float* op = outn + (size_t)(cb + lx) * HW + hw0 + lk * 4;
        #pragma unroll
        for (int nf = 0; nf < 4; ++nf) {
            float4 v;
            v.x = fmaxf(acc[nf][0] + bias, 0.0f);
            v.y = fmaxf(acc[nf][1] + bias, 0.0f);
            v.z = fmaxf(acc[nf][2] + bias, 0.0f);
            v.w = fmaxf(acc[nf][3] + bias, 0.0f);
            *(float4*)(op + nf * 16) = v;
        }
    }

    // ---- e3 (9 taps x K=64, halo is zero so loads are unconditional) ----
    {
        f32x4 acc[4] = {};
        #pragma unroll
        for (int j = 0; j < 9; ++j) {
            const int doff = (j / 3 - 1) * PROW + (j % 3 - 1);
            const unsigned short* wj = w3r_bf + j * 16384 + (cb + lx) * 64;
            bf16x8 b0 = *(const bf16x8*)(wj + lk * 8);
            bf16x8 b1v = *(const bf16x8*)(wj + 32 + lk * 8);
            #pragma unroll
            for (int nf = 0; nf < 4; ++nf) {
                int pt = pg[nf] + doff;
                int sw = (pt & 7) << 4;
                int base = tb[nf] + doff * 128;
                bf16x8 a0 = *(const bf16x8*)&tile[base + (lk16 ^ sw)];
                acc[nf] = __builtin_amdgcn_mfma_f32_16x16x32_bf16(a0, b0, acc[nf], 0, 0, 0);
                bf16x8 a1 = *(const bf16x8*)&tile[base + ((lk16 + 64) ^ sw)];
                acc[nf] = __builtin_amdgcn_mfma_f32_16x16x32_bf16(a1, b1v, acc[nf], 0, 0, 0);
            }
        }
        float bias = b3[cb + lx];
        float* op = outn + (size_t)(256 + cb + lx) * HW + hw0 + lk * 4;
        #pragma unroll
        for (int nf = 0; nf < 4; ++nf) {
            float4 v;
            v.x = fmaxf(acc[nf][0] + bias, 0.0f);
            v.y = fmaxf(acc[nf][1] + bias, 0.0f);
            v.z = fmaxf(acc[nf][2] + bias, 0.0f);
            v.w = fmaxf(acc[nf][3] + bias, 0.0f);
            *(float4*)(op + nf * 16) = v;
        }
    }
}

extern "C" void kernel_launch(void* const* d_in, const int* in_sizes, int n_in,
                              void* d_out, int out_size, void* d_ws, size_t ws_size,
                              hipStream_t stream) {
    const float* x   = (const float*)d_in[0];
    const float* wsq = (const float*)d_in[1];
    const float* bsq = (const float*)d_in[2];
    const float* w1  = (const float*)d_in[3];
    const float* b1  = (const float*)d_in[4];
    const float* w3  = (const float*)d_in[5];
    const float* b3  = (const float*)d_in[6];
    float* out = (float*)d_out;

    unsigned short* wsq_bf = (unsigned short*)d_ws;       // 32768 shorts
    unsigned short* w1_bf  = wsq_bf + 32768;              // 16384
    unsigned short* w3r_bf = w1_bf + 16384;               // 147456
    unsigned short* s      = w3r_bf + 147456;             // 32*3422*64 bf16 padded+swizzled

    zero_s<<<1712, 256, 0, stream>>>((uint4*)s);
    prep_weights<<<576, 256, 0, stream>>>(wsq, w1, w3, wsq_bf, w1_bf, w3r_bf);
    squeeze_kernel<<<dim3(49, 32), 256, 0, stream>>>(x, bsq, wsq_bf, s);
    expand_kernel<<<dim3(49, 4, 32), 256, 0, stream>>>(s, w1_bf, w3r_bf, b1, b3, out);
}